// Round 1
// baseline (239.583 us; speedup 1.0000x reference)
//
#include <hip/hip_runtime.h>
#include <hip/hip_bf16.h>

#define NROW 8192   // B*A = 64*128
#define INC  128
#define OUTC 64

typedef __bf16 bf16x8 __attribute__((ext_vector_type(8)));
typedef float  f32x4  __attribute__((ext_vector_type(4)));

static __device__ __forceinline__ f32x4 mfma16(bf16x8 a, bf16x8 b, f32x4 c) {
    return __builtin_amdgcn_mfma_f32_16x16x32_bf16(a, b, c, 0, 0, 0);
}

// ---------------------------------------------------------------------------
// Kernel 1: projection. f[r][c] = features[b][c][a] (r = b*128+a).
// q = f@Wq^T+bq, k = f@Wk^T+bk (row-major bf16), v stored transposed vT[c][r].
// Block = (b, quarter of a): stages f-tile (32 rows x 128 c) in LDS.
__global__ __launch_bounds__(256) void proj_kernel(
    const float* __restrict__ feat,
    const float* __restrict__ Wq, const float* __restrict__ bq,
    const float* __restrict__ Wk, const float* __restrict__ bk,
    const float* __restrict__ Wv, const float* __restrict__ bv,
    __hip_bfloat16* __restrict__ qb, __hip_bfloat16* __restrict__ kb,
    __hip_bfloat16* __restrict__ vT)
{
    __shared__ float flds[32 * 132];            // [a'][c], pad 132 vs bank conflicts
    const int blk = blockIdx.x;
    const int b   = blk >> 2;
    const int a0  = (blk & 3) * 32;
    const int r0  = b * 128 + a0;
    const float* fb = feat + (size_t)b * INC * 128;

    for (int i = threadIdx.x; i < 32 * 128; i += 256) {
        int c = i >> 5, a = i & 31;
        flds[a * 132 + c] = fb[c * 128 + a0 + a];
    }
    __syncthreads();

    const int w    = threadIdx.x >> 6;
    const int lane = threadIdx.x & 63;

    // Q and K: lane = output channel o, task = mat*32 + a'
    for (int task = w; task < 64; task += 4) {
        const int mat = task >> 5;
        const int a   = task & 31;
        const float* W = mat ? Wk : Wq;
        float acc = mat ? bk[lane] : bq[lane];
        const float* frow = flds + a * 132;
        const float* wrow = W + lane * INC;
        #pragma unroll 8
        for (int c4 = 0; c4 < INC; c4 += 4) {
            float4 f4 = *(const float4*)(frow + c4);
            float4 w4 = *(const float4*)(wrow + c4);
            acc += f4.x * w4.x + f4.y * w4.y + f4.z * w4.z + f4.w * w4.w;
        }
        __hip_bfloat16* dst = mat ? kb : qb;
        dst[(r0 + a) * OUTC + lane] = __float2bfloat16(acc);
    }

    // V: lane = row (so vT store is coalesced). Wave handles 2 channels at once.
    for (int t = w; t < 32; t += 4) {
        const int c  = t * 2 + (lane >> 5);
        const int ar = lane & 31;
        float acc = bv[c];
        const float* frow = flds + ar * 132;
        const float* wrow = Wv + c * INC;
        #pragma unroll 8
        for (int c4 = 0; c4 < INC; c4 += 4) {
            float4 f4 = *(const float4*)(frow + c4);
            float4 w4 = *(const float4*)(wrow + c4);
            acc += f4.x * w4.x + f4.y * w4.y + f4.z * w4.z + f4.w * w4.w;
        }
        vT[c * NROW + r0 + ar] = __float2bfloat16(acc);
    }
}

// ---------------------------------------------------------------------------
// Kernel 2: no-max exp-sum attention, split-K.
// task = g*256 + tile; wave owns rows [tile*32, tile*32+32), keys [g*2048, +2048).
// Opart[task][32][64] = sum_j exp2(coef*q.k_j) * v_j ; lpart[task][32] = sum_j exp2(...)
__global__ __launch_bounds__(64) void attn_kernel(
    const __hip_bfloat16* __restrict__ qb,
    const __hip_bfloat16* __restrict__ kb,
    const __hip_bfloat16* __restrict__ vT,
    float* __restrict__ Opart, float* __restrict__ lpart)
{
    __shared__ __align__(16) __hip_bfloat16 plds[2][16 * 40];  // P round-trip, pad 40
    const int task = blockIdx.x;
    const int tile = task & 255;
    const int g    = task >> 8;
    const int r0   = tile * 32;
    const int lane = threadIdx.x;
    const int l16  = lane & 15;
    const int quad = lane >> 4;

    bf16x8 qf[2][2];
    #pragma unroll
    for (int u = 0; u < 2; ++u)
        #pragma unroll
        for (int kc = 0; kc < 2; ++kc)
            qf[u][kc] = *(const bf16x8*)(qb + (r0 + u * 16 + l16) * 64 + kc * 32 + quad * 8);

    f32x4 of[2][4];
    float lp[2][4];
    #pragma unroll
    for (int u = 0; u < 2; ++u)
        #pragma unroll
        for (int n = 0; n < 4; ++n) {
            of[u][n] = (f32x4){0.f, 0.f, 0.f, 0.f};
            lp[u][n] = 0.f;
        }

    const float coef = 0.18033688011112042f;   // log2(e) / sqrt(64)
    int j0 = g * 2048;
    for (int it = 0; it < 64; ++it, j0 += 32) {
        bf16x8 kf[2][2];
        #pragma unroll
        for (int h = 0; h < 2; ++h)
            #pragma unroll
            for (int kc = 0; kc < 2; ++kc)
                kf[h][kc] = *(const bf16x8*)(kb + (j0 + h * 16 + l16) * 64 + kc * 32 + quad * 8);
        bf16x8 vf[4];
        #pragma unroll
        for (int n = 0; n < 4; ++n)
            vf[n] = *(const bf16x8*)(vT + (n * 16 + l16) * NROW + j0 + quad * 8);

        const f32x4 zero = (f32x4){0.f, 0.f, 0.f, 0.f};
        #pragma unroll
        for (int u = 0; u < 2; ++u) {
            f32x4 s0 = mfma16(qf[u][0], kf[0][0], zero);
            s0       = mfma16(qf[u][1], kf[0][1], s0);
            f32x4 s1 = mfma16(qf[u][0], kf[1][0], zero);
            s1       = mfma16(qf[u][1], kf[1][1], s1);
            __hip_bfloat16* pl = plds[u];
            #pragma unroll
            for (int r = 0; r < 4; ++r) {
                float p0 = exp2f(s0[r] * coef);
                float p1 = exp2f(s1[r] * coef);
                lp[u][r] += p0 + p1;
                int row = quad * 4 + r;                 // C-layout row
                pl[row * 40 + l16]      = __float2bfloat16(p0);
                pl[row * 40 + 16 + l16] = __float2bfloat16(p1);
            }
        }
        __syncthreads();    // P writes -> visible (single wave: just a waitcnt fence)
        #pragma unroll
        for (int u = 0; u < 2; ++u) {
            bf16x8 pf = *(const bf16x8*)(&plds[u][l16 * 40 + quad * 8]);  // A-layout
            #pragma unroll
            for (int n = 0; n < 4; ++n)
                of[u][n] = mfma16(pf, vf[n], of[u][n]);
        }
        __syncthreads();    // reads done before next iter overwrites plds
    }

    // reduce l across the 16 lanes of each quad (cols of the S tile)
    #pragma unroll
    for (int u = 0; u < 2; ++u)
        #pragma unroll
        for (int r = 0; r < 4; ++r) {
            float v = lp[u][r];
            v += __shfl_xor(v, 1, 64);
            v += __shfl_xor(v, 2, 64);
            v += __shfl_xor(v, 4, 64);
            v += __shfl_xor(v, 8, 64);
            lp[u][r] = v;
        }

    float* Ob = Opart + (size_t)task * 32 * 64;
    #pragma unroll
    for (int u = 0; u < 2; ++u)
        #pragma unroll
        for (int n = 0; n < 4; ++n)
            #pragma unroll
            for (int r = 0; r < 4; ++r)
                Ob[(u * 16 + quad * 4 + r) * 64 + n * 16 + l16] = of[u][n][r];
    if (l16 == 0) {
        #pragma unroll
        for (int u = 0; u < 2; ++u)
            #pragma unroll
            for (int r = 0; r < 4; ++r)
                lpart[task * 32 + u * 16 + quad * 4 + r] = lp[u][r];
    }
}

// ---------------------------------------------------------------------------
// Kernel 3: combine split-K partials, divide by l, l2-normalize rows -> qkvn (f32).
// One wave per row r (64 lanes = 64 cols).
__global__ __launch_bounds__(256) void combine_kernel(
    const float* __restrict__ Opart, const float* __restrict__ lpart,
    float* __restrict__ qkvn)
{
    const int r    = blockIdx.x * 4 + (threadIdx.x >> 6);
    const int c    = threadIdx.x & 63;
    const int tile = r >> 5, row = r & 31;
    float acc = 0.f, lsum = 0.f;
    #pragma unroll
    for (int g = 0; g < 4; ++g) {
        int task = g * 256 + tile;
        acc  += Opart[((size_t)task * 32 + row) * 64 + c];
        lsum += lpart[task * 32 + row];
    }
    float q = acc / lsum;
    float ss = q * q;
    ss += __shfl_xor(ss, 1, 64);
    ss += __shfl_xor(ss, 2, 64);
    ss += __shfl_xor(ss, 4, 64);
    ss += __shfl_xor(ss, 8, 64);
    ss += __shfl_xor(ss, 16, 64);
    ss += __shfl_xor(ss, 32, 64);
    qkvn[r * 64 + c] = q * rsqrtf(fmaxf(ss, 1e-24f));   // == q / max(||row||,1e-12)
}

// ---------------------------------------------------------------------------
// Kernel 4: per-row inverse norms of v (from vT).
__global__ __launch_bounds__(256) void invv_kernel(
    const __hip_bfloat16* __restrict__ vT, float* __restrict__ inv_v)
{
    const int r = blockIdx.x * 256 + threadIdx.x;
    float ss = 0.f;
    #pragma unroll 8
    for (int t = 0; t < 64; ++t) {
        float x = __bfloat162float(vT[t * NROW + r]);
        ss += x * x;
    }
    inv_v[r] = rsqrtf(fmaxf(ss, 1e-24f));
}

// ---------------------------------------------------------------------------
// Kernel 5: sim[b][cB] = (1/128) * sum_{a,t} v_n[b*128+a][t] * qkv_n[cB*128+a][t]
// Block = (b, cB). v-slab normalized into LDS as [a][t] (pad 65).
__global__ __launch_bounds__(256) void sim_kernel(
    const __hip_bfloat16* __restrict__ vT, const float* __restrict__ inv_v,
    const float* __restrict__ qkvn, float* __restrict__ out)
{
    __shared__ float vlds[128 * 65];
    __shared__ float red[4];
    const int b  = blockIdx.x >> 6;
    const int cB = blockIdx.x & 63;
    for (int i = threadIdx.x; i < 8192; i += 256) {
        int t = i >> 7, a = i & 127;
        vlds[a * 65 + t] = __bfloat162float(vT[t * NROW + b * 128 + a]) * inv_v[b * 128 + a];
    }
    __syncthreads();
    float acc = 0.f;
    const float* qbase = qkvn + cB * 128 * 64;
    #pragma unroll 4
    for (int j = 0; j < 32; ++j) {
        int e = j * 256 + threadIdx.x;
        int a = e >> 6, t = e & 63;
        acc += vlds[a * 65 + t] * qbase[e];   // qbase[a*64+t] == qbase[e]
    }
    acc += __shfl_xor(acc, 1, 64);
    acc += __shfl_xor(acc, 2, 64);
    acc += __shfl_xor(acc, 4, 64);
    acc += __shfl_xor(acc, 8, 64);
    acc += __shfl_xor(acc, 16, 64);
    acc += __shfl_xor(acc, 32, 64);
    if ((threadIdx.x & 63) == 0) red[threadIdx.x >> 6] = acc;
    __syncthreads();
    if (threadIdx.x == 0)
        out[b * 64 + cB] = (red[0] + red[1] + red[2] + red[3]) * (1.f / 128.f);
}

// ---------------------------------------------------------------------------
extern "C" void kernel_launch(void* const* d_in, const int* in_sizes, int n_in,
                              void* d_out, int out_size, void* d_ws, size_t ws_size,
                              hipStream_t stream)
{
    const float* feat = (const float*)d_in[0];
    const float* Wq   = (const float*)d_in[1];
    const float* bq   = (const float*)d_in[2];
    const float* Wk   = (const float*)d_in[3];
    const float* bk   = (const float*)d_in[4];
    const float* Wv   = (const float*)d_in[5];
    const float* bv   = (const float*)d_in[6];
    float* out = (float*)d_out;

    char* ws = (char*)d_ws;
    __hip_bfloat16* qb = (__hip_bfloat16*)(ws);                         // 1 MB
    __hip_bfloat16* kb = (__hip_bfloat16*)(ws + (1u << 20));            // 1 MB
    __hip_bfloat16* vT = (__hip_bfloat16*)(ws + (2u << 20));            // 1 MB
    float* Opart = (float*)(ws + (3u << 20));                           // 8 MB
    float* lpart = (float*)(ws + (11u << 20));                          // 128 KB
    float* qkvn  = (float*)(ws + (11u << 20) + (1u << 17));             // 2 MB
    float* inv_v = (float*)(ws + (13u << 20) + (1u << 17));             // 32 KB

    proj_kernel<<<256, 256, 0, stream>>>(feat, Wq, bq, Wk, bk, Wv, bv, qb, kb, vT);
    attn_kernel<<<1024, 64, 0, stream>>>(qb, kb, vT, Opart, lpart);
    combine_kernel<<<2048, 256, 0, stream>>>(Opart, lpart, qkvn);
    invv_kernel<<<32, 256, 0, stream>>>(vT, inv_v);
    sim_kernel<<<4096, 256, 0, stream>>>(vT, inv_v, qkvn, out);
}

// Round 2
// 167.172 us; speedup vs baseline: 1.4332x; 1.4332x over previous
//
#include <hip/hip_runtime.h>
#include <hip/hip_bf16.h>

#define NROW 8192   // B*A = 64*128
#define INC  128
#define OUTC 64

typedef __bf16 bf16x8 __attribute__((ext_vector_type(8)));
typedef float  f32x4  __attribute__((ext_vector_type(4)));

static __device__ __forceinline__ f32x4 mfma16(bf16x8 a, bf16x8 b, f32x4 c) {
    return __builtin_amdgcn_mfma_f32_16x16x32_bf16(a, b, c, 0, 0, 0);
}

static __device__ __forceinline__ bf16x8 cvt8(float4 lo, float4 hi) {
    bf16x8 r;
    r[0] = (__bf16)lo.x; r[1] = (__bf16)lo.y; r[2] = (__bf16)lo.z; r[3] = (__bf16)lo.w;
    r[4] = (__bf16)hi.x; r[5] = (__bf16)hi.y; r[6] = (__bf16)hi.z; r[7] = (__bf16)hi.w;
    return r;
}

// ---------------------------------------------------------------------------
// Kernel 1: projection via MFMA. grid = 768 = mat(3) x b(64) x aq(4).
// Block: 256 thr (4 waves, each a 16-wide N stripe). M=32 rows, K=128.
// mat 0 -> q (row-major bf16), 1 -> k, 2 -> vT (transposed) + fused inv_v.
__global__ __launch_bounds__(256) void proj_kernel(
    const float* __restrict__ feat,
    const float* __restrict__ Wq, const float* __restrict__ bq,
    const float* __restrict__ Wk, const float* __restrict__ bk,
    const float* __restrict__ Wv, const float* __restrict__ bv,
    __hip_bfloat16* __restrict__ qb, __hip_bfloat16* __restrict__ kb,
    __hip_bfloat16* __restrict__ vT, float* __restrict__ inv_v)
{
    __shared__ float slab[32 * 132];   // f[a][c], pad-132
    __shared__ float vbuf[32 * 66];    // V transpose staging [r][c], pad-66

    const int blk = blockIdx.x;
    const int mat = blk >> 8;                 // 0,1,2
    const int b   = (blk >> 2) & 63;
    const int a0  = (blk & 3) * 32;
    const int r0  = b * 128 + a0;
    const float* fb = feat + (size_t)b * INC * 128;

    for (int i = threadIdx.x; i < 32 * 128; i += 256) {
        int c = i >> 5, a = i & 31;
        slab[a * 132 + c] = fb[c * 128 + a0 + a];
    }
    __syncthreads();

    const int w    = threadIdx.x >> 6;
    const int lane = threadIdx.x & 63;
    const int l16  = lane & 15;
    const int quad = lane >> 4;
    const int n0   = w * 16;

    const float* W    = (mat == 0) ? Wq : (mat == 1) ? Wk : Wv;
    const float* bias = (mat == 0) ? bq : (mat == 1) ? bk : bv;

    f32x4 acc[2] = {{0.f,0.f,0.f,0.f},{0.f,0.f,0.f,0.f}};
    #pragma unroll
    for (int kc = 0; kc < 4; ++kc) {
        const int k0 = kc * 32 + quad * 8;
        const float* wr = W + (n0 + l16) * INC + k0;
        bf16x8 bfr = cvt8(*(const float4*)wr, *(const float4*)(wr + 4));
        #pragma unroll
        for (int u = 0; u < 2; ++u) {
            const float* ar = slab + (u * 16 + l16) * 132 + k0;
            bf16x8 afr = cvt8(*(const float4*)ar, *(const float4*)(ar + 4));
            acc[u] = mfma16(afr, bfr, acc[u]);
        }
    }
    const float bl = bias[n0 + l16];

    if (mat < 2) {
        __hip_bfloat16* dst = mat ? kb : qb;
        #pragma unroll
        for (int u = 0; u < 2; ++u)
            #pragma unroll
            for (int r = 0; r < 4; ++r)
                dst[(r0 + u * 16 + quad * 4 + r) * OUTC + n0 + l16] =
                    __float2bfloat16(acc[u][r] + bl);
    } else {
        #pragma unroll
        for (int u = 0; u < 2; ++u)
            #pragma unroll
            for (int r = 0; r < 4; ++r)
                vbuf[(u * 16 + quad * 4 + r) * 66 + n0 + l16] = acc[u][r] + bl;
        __syncthreads();
        // coalesced transposed store: thread -> (c = tid>>2, rchunk = tid&3)
        const int c  = threadIdx.x >> 2;
        const int rc = threadIdx.x & 3;
        bf16x8 pack;
        #pragma unroll
        for (int i = 0; i < 8; ++i)
            pack[i] = (__bf16)vbuf[(rc * 8 + i) * 66 + c];
        *(bf16x8*)(vT + (size_t)c * NROW + r0 + rc * 8) = pack;
        // fused inv_v: thread (r = tid>>3, j = tid&7) partial-sums 8 cols
        const int rr = threadIdx.x >> 3;
        const int jj = threadIdx.x & 7;
        float ss = 0.f;
        #pragma unroll
        for (int i = 0; i < 8; ++i) {
            float x = vbuf[rr * 66 + jj * 8 + i];
            ss += x * x;
        }
        ss += __shfl_xor(ss, 1, 64);
        ss += __shfl_xor(ss, 2, 64);
        ss += __shfl_xor(ss, 4, 64);
        if (jj == 0) inv_v[r0 + rr] = rsqrtf(fmaxf(ss, 1e-24f));
    }
}

// ---------------------------------------------------------------------------
// Kernel 2: no-max exp-sum attention, split-K (G=4).
// task = g*256 + tile; wave owns rows [tile*32, +32), keys [g*2048, +2048).
__global__ __launch_bounds__(64) void attn_kernel(
    const __hip_bfloat16* __restrict__ qb,
    const __hip_bfloat16* __restrict__ kb,
    const __hip_bfloat16* __restrict__ vT,
    float* __restrict__ Opart, float* __restrict__ lpart)
{
    __shared__ __align__(16) __hip_bfloat16 plds[2][16 * 40];  // P round-trip, pad 40
    const int task = blockIdx.x;
    const int tile = task & 255;
    const int g    = task >> 8;
    const int r0   = tile * 32;
    const int lane = threadIdx.x;
    const int l16  = lane & 15;
    const int quad = lane >> 4;

    bf16x8 qf[2][2];
    #pragma unroll
    for (int u = 0; u < 2; ++u)
        #pragma unroll
        for (int kc = 0; kc < 2; ++kc)
            qf[u][kc] = *(const bf16x8*)(qb + (r0 + u * 16 + l16) * 64 + kc * 32 + quad * 8);

    f32x4 of[2][4];
    float lp[2][4];
    #pragma unroll
    for (int u = 0; u < 2; ++u)
        #pragma unroll
        for (int n = 0; n < 4; ++n) {
            of[u][n] = (f32x4){0.f, 0.f, 0.f, 0.f};
            lp[u][n] = 0.f;
        }

    const float coef = 0.18033688011112042f;   // log2(e) / sqrt(64)
    int j0 = g * 2048;
    for (int it = 0; it < 64; ++it, j0 += 32) {
        bf16x8 kf[2][2];
        #pragma unroll
        for (int h = 0; h < 2; ++h)
            #pragma unroll
            for (int kc = 0; kc < 2; ++kc)
                kf[h][kc] = *(const bf16x8*)(kb + (j0 + h * 16 + l16) * 64 + kc * 32 + quad * 8);
        bf16x8 vf[4];
        #pragma unroll
        for (int n = 0; n < 4; ++n)
            vf[n] = *(const bf16x8*)(vT + (n * 16 + l16) * NROW + j0 + quad * 8);

        const f32x4 zero = (f32x4){0.f, 0.f, 0.f, 0.f};
        #pragma unroll
        for (int u = 0; u < 2; ++u) {
            f32x4 s0 = mfma16(qf[u][0], kf[0][0], zero);
            s0       = mfma16(qf[u][1], kf[0][1], s0);
            f32x4 s1 = mfma16(qf[u][0], kf[1][0], zero);
            s1       = mfma16(qf[u][1], kf[1][1], s1);
            __hip_bfloat16* pl = plds[u];
            #pragma unroll
            for (int r = 0; r < 4; ++r) {
                float p0 = exp2f(s0[r] * coef);
                float p1 = exp2f(s1[r] * coef);
                lp[u][r] += p0 + p1;
                int row = quad * 4 + r;                 // C-layout row
                pl[row * 40 + l16]      = __float2bfloat16(p0);
                pl[row * 40 + 16 + l16] = __float2bfloat16(p1);
            }
        }
        __syncthreads();
        #pragma unroll
        for (int u = 0; u < 2; ++u) {
            bf16x8 pf = *(const bf16x8*)(&plds[u][l16 * 40 + quad * 8]);  // A-layout
            #pragma unroll
            for (int n = 0; n < 4; ++n)
                of[u][n] = mfma16(pf, vf[n], of[u][n]);
        }
        __syncthreads();
    }

    #pragma unroll
    for (int u = 0; u < 2; ++u)
        #pragma unroll
        for (int r = 0; r < 4; ++r) {
            float v = lp[u][r];
            v += __shfl_xor(v, 1, 64);
            v += __shfl_xor(v, 2, 64);
            v += __shfl_xor(v, 4, 64);
            v += __shfl_xor(v, 8, 64);
            lp[u][r] = v;
        }

    float* Ob = Opart + (size_t)task * 32 * 64;
    #pragma unroll
    for (int u = 0; u < 2; ++u)
        #pragma unroll
        for (int n = 0; n < 4; ++n)
            #pragma unroll
            for (int r = 0; r < 4; ++r)
                Ob[(u * 16 + quad * 4 + r) * 64 + n * 16 + l16] = of[u][n][r];
    if (l16 == 0) {
        #pragma unroll
        for (int u = 0; u < 2; ++u)
            #pragma unroll
            for (int r = 0; r < 4; ++r)
                lpart[task * 32 + u * 16 + quad * 4 + r] = lp[u][r];
    }
}

// ---------------------------------------------------------------------------
// Kernel 3: combine split-K partials, divide by l, l2-normalize rows -> qkvn.
__global__ __launch_bounds__(256) void combine_kernel(
    const float* __restrict__ Opart, const float* __restrict__ lpart,
    float* __restrict__ qkvn)
{
    const int r    = blockIdx.x * 4 + (threadIdx.x >> 6);
    const int c    = threadIdx.x & 63;
    const int tile = r >> 5, row = r & 31;
    float acc = 0.f, lsum = 0.f;
    #pragma unroll
    for (int g = 0; g < 4; ++g) {
        int task = g * 256 + tile;
        acc  += Opart[((size_t)task * 32 + row) * 64 + c];
        lsum += lpart[task * 32 + row];
    }
    float q = acc / lsum;
    float ss = q * q;
    ss += __shfl_xor(ss, 1, 64);
    ss += __shfl_xor(ss, 2, 64);
    ss += __shfl_xor(ss, 4, 64);
    ss += __shfl_xor(ss, 8, 64);
    ss += __shfl_xor(ss, 16, 64);
    ss += __shfl_xor(ss, 32, 64);
    qkvn[r * 64 + c] = q * rsqrtf(fmaxf(ss, 1e-24f));
}

// ---------------------------------------------------------------------------
// Kernel 4: sim[b][cB] = (1/128) * sum_{a,t} v_n[b*128+a][t] * qkv_n[cB*128+a][t]
__global__ __launch_bounds__(256) void sim_kernel(
    const __hip_bfloat16* __restrict__ vT, const float* __restrict__ inv_v,
    const float* __restrict__ qkvn, float* __restrict__ out)
{
    __shared__ float vlds[128 * 65];
    __shared__ float red[4];
    const int b  = blockIdx.x >> 6;
    const int cB = blockIdx.x & 63;
    for (int i = threadIdx.x; i < 8192; i += 256) {
        int t = i >> 7, a = i & 127;
        vlds[a * 65 + t] = __bfloat162float(vT[t * NROW + b * 128 + a]) * inv_v[b * 128 + a];
    }
    __syncthreads();
    float acc = 0.f;
    const float* qbase = qkvn + cB * 128 * 64;
    #pragma unroll 4
    for (int j = 0; j < 32; ++j) {
        int e = j * 256 + threadIdx.x;
        int a = e >> 6, t = e & 63;
        acc += vlds[a * 65 + t] * qbase[e];
    }
    acc += __shfl_xor(acc, 1, 64);
    acc += __shfl_xor(acc, 2, 64);
    acc += __shfl_xor(acc, 4, 64);
    acc += __shfl_xor(acc, 8, 64);
    acc += __shfl_xor(acc, 16, 64);
    acc += __shfl_xor(acc, 32, 64);
    if ((threadIdx.x & 63) == 0) red[threadIdx.x >> 6] = acc;
    __syncthreads();
    if (threadIdx.x == 0)
        out[b * 64 + cB] = (red[0] + red[1] + red[2] + red[3]) * (1.f / 128.f);
}

// ---------------------------------------------------------------------------
extern "C" void kernel_launch(void* const* d_in, const int* in_sizes, int n_in,
                              void* d_out, int out_size, void* d_ws, size_t ws_size,
                              hipStream_t stream)
{
    const float* feat = (const float*)d_in[0];
    const float* Wq   = (const float*)d_in[1];
    const float* bq   = (const float*)d_in[2];
    const float* Wk   = (const float*)d_in[3];
    const float* bk   = (const float*)d_in[4];
    const float* Wv   = (const float*)d_in[5];
    const float* bv   = (const float*)d_in[6];
    float* out = (float*)d_out;

    char* ws = (char*)d_ws;
    __hip_bfloat16* qb = (__hip_bfloat16*)(ws);                         // 1 MB
    __hip_bfloat16* kb = (__hip_bfloat16*)(ws + (1u << 20));            // 1 MB
    __hip_bfloat16* vT = (__hip_bfloat16*)(ws + (2u << 20));            // 1 MB
    float* Opart = (float*)(ws + (3u << 20));                           // 8 MB
    float* lpart = (float*)(ws + (11u << 20));                          // 128 KB
    float* qkvn  = (float*)(ws + (11u << 20) + (1u << 17));             // 2 MB
    float* inv_v = (float*)(ws + (13u << 20) + (1u << 17));             // 32 KB

    proj_kernel<<<768, 256, 0, stream>>>(feat, Wq, bq, Wk, bk, Wv, bv, qb, kb, vT, inv_v);
    attn_kernel<<<1024, 64, 0, stream>>>(qb, kb, vT, Opart, lpart);
    combine_kernel<<<2048, 256, 0, stream>>>(Opart, lpart, qkvn);
    sim_kernel<<<4096, 256, 0, stream>>>(vT, inv_v, qkvn, out);
}

// Round 5
// 157.877 us; speedup vs baseline: 1.5175x; 1.0589x over previous
//
#include <hip/hip_runtime.h>
#include <hip/hip_bf16.h>

#define NROW 8192   // B*A = 64*128
#define INC  128
#define OUTC 64

typedef __bf16 bf16x8 __attribute__((ext_vector_type(8)));
typedef __bf16 bf16x2 __attribute__((ext_vector_type(2)));
typedef float  f32x4  __attribute__((ext_vector_type(4)));

static __device__ __forceinline__ f32x4 mfma16(bf16x8 a, bf16x8 b, f32x4 c) {
    return __builtin_amdgcn_mfma_f32_16x16x32_bf16(a, b, c, 0, 0, 0);
}

static __device__ __forceinline__ bf16x8 cvt8(float4 lo, float4 hi) {
    bf16x8 r;
    r[0] = (__bf16)lo.x; r[1] = (__bf16)lo.y; r[2] = (__bf16)lo.z; r[3] = (__bf16)lo.w;
    r[4] = (__bf16)hi.x; r[5] = (__bf16)hi.y; r[6] = (__bf16)hi.z; r[7] = (__bf16)hi.w;
    return r;
}

// ---------------------------------------------------------------------------
// Kernel 1: projection via MFMA. grid = 768 = mat(3) x b(64) x aq(4).
// mat 0 -> q, 1 -> k (row-major bf16), 2 -> vT (transposed) + normalized vnb.
__global__ __launch_bounds__(256) void proj_kernel(
    const float* __restrict__ feat,
    const float* __restrict__ Wq, const float* __restrict__ bq,
    const float* __restrict__ Wk, const float* __restrict__ bk,
    const float* __restrict__ Wv, const float* __restrict__ bv,
    __hip_bfloat16* __restrict__ qb, __hip_bfloat16* __restrict__ kb,
    __hip_bfloat16* __restrict__ vT, __hip_bfloat16* __restrict__ vnb)
{
    __shared__ float slab[32 * 132];   // f[a][c], pad-132
    __shared__ float vbuf[32 * 66];    // V staging [r][c], pad-66
    __shared__ float invb[32];

    const int blk = blockIdx.x;
    const int mat = blk >> 8;                 // 0,1,2
    const int b   = (blk >> 2) & 63;
    const int a0  = (blk & 3) * 32;
    const int r0  = b * 128 + a0;
    const float* fb = feat + (size_t)b * INC * 128;

    for (int i = threadIdx.x; i < 32 * 128; i += 256) {
        int c = i >> 5, a = i & 31;
        slab[a * 132 + c] = fb[c * 128 + a0 + a];
    }
    __syncthreads();

    const int w    = threadIdx.x >> 6;
    const int lane = threadIdx.x & 63;
    const int l16  = lane & 15;
    const int quad = lane >> 4;
    const int n0   = w * 16;

    const float* W    = (mat == 0) ? Wq : (mat == 1) ? Wk : Wv;
    const float* bias = (mat == 0) ? bq : (mat == 1) ? bk : bv;

    f32x4 acc[2] = {{0.f,0.f,0.f,0.f},{0.f,0.f,0.f,0.f}};
    #pragma unroll
    for (int kc = 0; kc < 4; ++kc) {
        const int k0 = kc * 32 + quad * 8;
        const float* wr = W + (n0 + l16) * INC + k0;
        bf16x8 bfr = cvt8(*(const float4*)wr, *(const float4*)(wr + 4));
        #pragma unroll
        for (int u = 0; u < 2; ++u) {
            const float* ar = slab + (u * 16 + l16) * 132 + k0;
            bf16x8 afr = cvt8(*(const float4*)ar, *(const float4*)(ar + 4));
            acc[u] = mfma16(afr, bfr, acc[u]);
        }
    }
    const float bl = bias[n0 + l16];

    if (mat < 2) {
        __hip_bfloat16* dst = mat ? kb : qb;
        #pragma unroll
        for (int u = 0; u < 2; ++u)
            #pragma unroll
            for (int r = 0; r < 4; ++r)
                dst[(r0 + u * 16 + quad * 4 + r) * OUTC + n0 + l16] =
                    __float2bfloat16(acc[u][r] + bl);
    } else {
        #pragma unroll
        for (int u = 0; u < 2; ++u)
            #pragma unroll
            for (int r = 0; r < 4; ++r)
                vbuf[(u * 16 + quad * 4 + r) * 66 + n0 + l16] = acc[u][r] + bl;
        __syncthreads();
        // coalesced transposed store for attention's vT
        const int c  = threadIdx.x >> 2;
        const int rc = threadIdx.x & 3;
        bf16x8 pack;
        #pragma unroll
        for (int i = 0; i < 8; ++i)
            pack[i] = (__bf16)vbuf[(rc * 8 + i) * 66 + c];
        *(bf16x8*)(vT + (size_t)c * NROW + r0 + rc * 8) = pack;
        // row norms: thread (rl = tid>>3, jj = tid&7)
        const int rl = threadIdx.x >> 3;
        const int jj = threadIdx.x & 7;
        float ss = 0.f;
        #pragma unroll
        for (int i = 0; i < 8; ++i) {
            float x = vbuf[rl * 66 + jj * 8 + i];
            ss += x * x;
        }
        ss += __shfl_xor(ss, 1, 64);
        ss += __shfl_xor(ss, 2, 64);
        ss += __shfl_xor(ss, 4, 64);
        if (jj == 0) invb[rl] = rsqrtf(fmaxf(ss, 1e-24f));
        __syncthreads();   // real barrier: cross-lane LDS write -> read ordering
        float inv = invb[rl];
        bf16x8 vp;
        #pragma unroll
        for (int i = 0; i < 8; ++i)
            vp[i] = (__bf16)(vbuf[rl * 66 + jj * 8 + i] * inv);
        *(bf16x8*)(vnb + (size_t)(r0 + rl) * 64 + jj * 8) = vp;
    }
}

// ---------------------------------------------------------------------------
// Kernel 2: no-max exp-sum attention, split-K (G groups, kpg keys each).
// Even/odd key interleave -> packed b32 P writes. Double-buffered P tile:
// ONE __syncthreads per iteration (write buf -> barrier -> read buf; next
// iteration writes the other buffer, so no write-after-read hazard).
__global__ __launch_bounds__(64, 4) void attn_kernel(
    const __hip_bfloat16* __restrict__ qb,
    const __hip_bfloat16* __restrict__ kb,
    const __hip_bfloat16* __restrict__ vT,
    float* __restrict__ Opart, float* __restrict__ lpart, int kpg)
{
    __shared__ __align__(16) __bf16 plds[2][2][16 * 40];  // [buf][m-blk][16 x pad40]
    const int task = blockIdx.x;
    const int tile = task & 255;
    const int g    = task >> 8;
    const int r0   = tile * 32;
    const int lane = threadIdx.x;
    const int l16  = lane & 15;
    const int quad = lane >> 4;

    bf16x8 qf[2][2];
    #pragma unroll
    for (int u = 0; u < 2; ++u)
        #pragma unroll
        for (int kc = 0; kc < 2; ++kc)
            qf[u][kc] = *(const bf16x8*)(qb + (r0 + u * 16 + l16) * 64 + kc * 32 + quad * 8);

    f32x4 of[2][4];
    float lp[2][4];
    #pragma unroll
    for (int u = 0; u < 2; ++u)
        #pragma unroll
        for (int n = 0; n < 4; ++n) {
            of[u][n] = (f32x4){0.f, 0.f, 0.f, 0.f};
            lp[u][n] = 0.f;
        }

    const float coef = 0.18033688011112042f;   // log2(e) / sqrt(64)
    const int iters = kpg >> 5;
    int j0 = g * kpg;

    bf16x8 kfc[2][2];
    #pragma unroll
    for (int h = 0; h < 2; ++h)
        #pragma unroll
        for (int kc = 0; kc < 2; ++kc)
            kfc[h][kc] = *(const bf16x8*)(kb + (size_t)(j0 + 2 * l16 + h) * 64 + kc * 32 + quad * 8);

    for (int it = 0; it < iters; ++it) {
        bf16x8 vf[4];
        #pragma unroll
        for (int n = 0; n < 4; ++n)
            vf[n] = *(const bf16x8*)(vT + (size_t)(n * 16 + l16) * NROW + j0 + quad * 8);
        const int jn = (it + 1 < iters) ? j0 + 32 : j0;
        bf16x8 kfn[2][2];
        #pragma unroll
        for (int h = 0; h < 2; ++h)
            #pragma unroll
            for (int kc = 0; kc < 2; ++kc)
                kfn[h][kc] = *(const bf16x8*)(kb + (size_t)(jn + 2 * l16 + h) * 64 + kc * 32 + quad * 8);

        __bf16* pbuf = &plds[it & 1][0][0];
        const f32x4 zero = (f32x4){0.f, 0.f, 0.f, 0.f};
        #pragma unroll
        for (int u = 0; u < 2; ++u) {
            f32x4 s0 = mfma16(qf[u][0], kfc[0][0], zero);   // even keys
            s0       = mfma16(qf[u][1], kfc[0][1], s0);
            f32x4 s1 = mfma16(qf[u][0], kfc[1][0], zero);   // odd keys
            s1       = mfma16(qf[u][1], kfc[1][1], s1);
            __bf16* pl = pbuf + u * (16 * 40);
            #pragma unroll
            for (int r = 0; r < 4; ++r) {
                float p0 = exp2f(s0[r] * coef);
                float p1 = exp2f(s1[r] * coef);
                lp[u][r] += p0 + p1;
                int row = quad * 4 + r;                     // C-layout row
                bf16x2 pp; pp[0] = (__bf16)p0; pp[1] = (__bf16)p1;
                *(bf16x2*)(&pl[row * 40 + 2 * l16]) = pp;
            }
        }
        __syncthreads();   // write -> read ordering (also a compiler fence)
        #pragma unroll
        for (int u = 0; u < 2; ++u) {
            bf16x8 pf = *(const bf16x8*)(&pbuf[u * (16 * 40) + l16 * 40 + quad * 8]);
            #pragma unroll
            for (int n = 0; n < 4; ++n)
                of[u][n] = mfma16(pf, vf[n], of[u][n]);
        }
        #pragma unroll
        for (int h = 0; h < 2; ++h)
            #pragma unroll
            for (int kc = 0; kc < 2; ++kc)
                kfc[h][kc] = kfn[h][kc];
        j0 += 32;
    }

    #pragma unroll
    for (int u = 0; u < 2; ++u)
        #pragma unroll
        for (int r = 0; r < 4; ++r) {
            float v = lp[u][r];
            v += __shfl_xor(v, 1, 64);
            v += __shfl_xor(v, 2, 64);
            v += __shfl_xor(v, 4, 64);
            v += __shfl_xor(v, 8, 64);
            lp[u][r] = v;
        }

    float* Ob = Opart + (size_t)task * 32 * 64;
    #pragma unroll
    for (int u = 0; u < 2; ++u)
        #pragma unroll
        for (int n = 0; n < 4; ++n)
            #pragma unroll
            for (int r = 0; r < 4; ++r)
                Ob[(u * 16 + quad * 4 + r) * 64 + n * 16 + l16] = of[u][n][r];
    if (l16 == 0) {
        #pragma unroll
        for (int u = 0; u < 2; ++u)
            #pragma unroll
            for (int r = 0; r < 4; ++r)
                lpart[task * 32 + u * 16 + quad * 4 + r] = lp[u][r];
    }
}

// ---------------------------------------------------------------------------
// Kernel 3: combine split-K partials, divide by l, l2-normalize -> qnb (bf16).
__global__ __launch_bounds__(256) void combine_kernel(
    const float* __restrict__ Opart, const float* __restrict__ lpart,
    __hip_bfloat16* __restrict__ qnb, int G)
{
    const int r    = blockIdx.x * 4 + (threadIdx.x >> 6);
    const int c    = threadIdx.x & 63;
    const int tile = r >> 5, row = r & 31;
    float acc = 0.f, lsum = 0.f;
    for (int g = 0; g < G; ++g) {
        int task = g * 256 + tile;
        acc  += Opart[((size_t)task * 32 + row) * 64 + c];
        lsum += lpart[task * 32 + row];
    }
    float q = acc / lsum;
    float ss = q * q;
    ss += __shfl_xor(ss, 1, 64);
    ss += __shfl_xor(ss, 2, 64);
    ss += __shfl_xor(ss, 4, 64);
    ss += __shfl_xor(ss, 8, 64);
    ss += __shfl_xor(ss, 16, 64);
    ss += __shfl_xor(ss, 32, 64);
    qnb[(size_t)r * 64 + c] = __float2bfloat16(q * rsqrtf(fmaxf(ss, 1e-24f)));
}

// ---------------------------------------------------------------------------
// Kernel 4: sim = (1/128) * Vn(64x8192) @ Qn(64x8192)^T, split-K MFMA GEMM.
// vnb/qnb row-major [r][t] == flat [64][8192]. 128 blocks x 64 k each.
__global__ __launch_bounds__(64) void sim_kernel(
    const __hip_bfloat16* __restrict__ vnb,
    const __hip_bfloat16* __restrict__ qnb,
    float* __restrict__ out)
{
    const int lane = threadIdx.x;
    const int l16  = lane & 15;
    const int quad = lane >> 4;
    const int kblk = blockIdx.x * 64;

    f32x4 acc[4][4];
    #pragma unroll
    for (int mi = 0; mi < 4; ++mi)
        #pragma unroll
        for (int ni = 0; ni < 4; ++ni)
            acc[mi][ni] = (f32x4){0.f, 0.f, 0.f, 0.f};

    #pragma unroll
    for (int ks = 0; ks < 2; ++ks) {
        const int k0 = kblk + ks * 32 + quad * 8;
        bf16x8 af[4], bfv[4];
        #pragma unroll
        for (int mi = 0; mi < 4; ++mi)
            af[mi] = *(const bf16x8*)(vnb + (size_t)(mi * 16 + l16) * 8192 + k0);
        #pragma unroll
        for (int ni = 0; ni < 4; ++ni)
            bfv[ni] = *(const bf16x8*)(qnb + (size_t)(ni * 16 + l16) * 8192 + k0);
        #pragma unroll
        for (int mi = 0; mi < 4; ++mi)
            #pragma unroll
            for (int ni = 0; ni < 4; ++ni)
                acc[mi][ni] = mfma16(af[mi], bfv[ni], acc[mi][ni]);
    }

    #pragma unroll
    for (int mi = 0; mi < 4; ++mi)
        #pragma unroll
        for (int ni = 0; ni < 4; ++ni)
            #pragma unroll
            for (int r = 0; r < 4; ++r)
                atomicAdd(&out[(mi * 16 + quad * 4 + r) * 64 + ni * 16 + l16],
                          acc[mi][ni][r] * (1.f / 128.f));
}

// ---------------------------------------------------------------------------
extern "C" void kernel_launch(void* const* d_in, const int* in_sizes, int n_in,
                              void* d_out, int out_size, void* d_ws, size_t ws_size,
                              hipStream_t stream)
{
    const float* feat = (const float*)d_in[0];
    const float* Wq   = (const float*)d_in[1];
    const float* bq   = (const float*)d_in[2];
    const float* Wk   = (const float*)d_in[3];
    const float* bk   = (const float*)d_in[4];
    const float* Wv   = (const float*)d_in[5];
    const float* bv   = (const float*)d_in[6];
    float* out = (float*)d_out;

    const size_t MB = 1u << 20;
    // pick split-K factor by available workspace (ws_size is constant per run)
    int G = 16;
    if (ws_size < 5 * MB + 16 * (2 * MB + 32 * 1024)) G = 4;
    const int kpg = NROW / G;

    char* ws = (char*)d_ws;
    __hip_bfloat16* qb  = (__hip_bfloat16*)(ws);             // 1 MB
    __hip_bfloat16* kb  = (__hip_bfloat16*)(ws + 1 * MB);    // 1 MB
    __hip_bfloat16* vT  = (__hip_bfloat16*)(ws + 2 * MB);    // 1 MB
    __hip_bfloat16* vnb = (__hip_bfloat16*)(ws + 3 * MB);    // 1 MB
    __hip_bfloat16* qnb = (__hip_bfloat16*)(ws + 4 * MB);    // 1 MB
    float* Opart = (float*)(ws + 5 * MB);                    // G*2 MB
    float* lpart = (float*)(ws + 5 * MB + (size_t)G * 2 * MB); // G*32 KB

    (void)hipMemsetAsync(out, 0, 64 * 64 * sizeof(float), stream);
    proj_kernel<<<768, 256, 0, stream>>>(feat, Wq, bq, Wk, bk, Wv, bv, qb, kb, vT, vnb);
    attn_kernel<<<G * 256, 64, 0, stream>>>(qb, kb, vT, Opart, lpart, kpg);
    combine_kernel<<<2048, 256, 0, stream>>>(Opart, lpart, qnb, G);
    sim_kernel<<<128, 64, 0, stream>>>(vnb, qnb, out);
}